// Round 8
// baseline (603.644 us; speedup 1.0000x reference)
//
#include <hip/hip_runtime.h>
#include <math.h>

// Problem constants
#define NJ   24
#define JD   3
#define TS   120
#define B_TOT 16384
#define CT   (NJ * JD * TS)     // 8640 floats per batch row
#define CT4  (CT / 4)           // 2160 float4 per row
#define FL4_TOT ((long)B_TOT * CT4)  // 35,389,440 float4 total
#define NBLK 2160               // blocks; 2160*256 threads
#define THREADS (NBLK * 256)    // 552,960; THREADS % CT4 == 0 -> fixed per-thread position
#define ITERS ((int)(FL4_TOT / THREADS))  // 64, exact

typedef float vfloat4 __attribute__((ext_vector_type(4)));

// zero the 8640 accumulators + the ticket counter (ws is NOT re-poisoned
// between replays -> must zero every call)
__global__ void pj_zero(float* __restrict__ sq) {
    int i = blockIdx.x * blockDim.x + threadIdx.x;
    if (i < CT + 1) sq[i] = 0.0f;   // sq[CT] doubles as the ticket (int 0)
}

// R7 streaming structure (frozen: nt loads, 1 float4/thread, fixed position,
// register accum) + fused last-block finalize.
__global__ __launch_bounds__(256) void pj_accum(const float* __restrict__ src,
                                                const float* __restrict__ tgt,
                                                float* __restrict__ sq,
                                                float* __restrict__ out) {
    int tid = blockIdx.x * 256 + threadIdx.x;
    int p = tid % CT4;              // fixed row-position of this thread
    const vfloat4* s = (const vfloat4*)src;
    const vfloat4* t = (const vfloat4*)tgt;
    long k = tid;
    float ax = 0.f, ay = 0.f, az = 0.f, aw = 0.f;
    #pragma unroll 8
    for (int j = 0; j < ITERS; ++j) {
        vfloat4 a = __builtin_nontemporal_load(&s[k]);
        vfloat4 c = __builtin_nontemporal_load(&t[k]);
        vfloat4 d = a - c;
        ax += d.x * d.x; ay += d.y * d.y; az += d.z * d.z; aw += d.w * d.w;
        k += THREADS;
    }
    atomicAdd(&sq[p * 4 + 0], ax);
    atomicAdd(&sq[p * 4 + 1], ay);
    atomicAdd(&sq[p * 4 + 2], az);
    atomicAdd(&sq[p * 4 + 3], aw);

    // ---- last-block finalize (device-scope, XCD-coherence-safe) ----
    __threadfence();                 // make this thread's atomics device-visible
    __syncthreads();                 // whole block's atomics fenced
    __shared__ int amLast;
    if (threadIdx.x == 0) {
        unsigned old = atomicAdd((unsigned*)&sq[CT], 1u);
        amLast = (old == NBLK - 1);
    }
    __syncthreads();
    if (!amLast) return;

    float local = 0.0f;
    for (int i = threadIdx.x; i < NJ * TS; i += 256) {
        int n = i / TS, t = i - n * TS;
        float s0 = __hip_atomic_load(&sq[(3 * n + 0) * TS + t], __ATOMIC_RELAXED, __HIP_MEMORY_SCOPE_AGENT);
        float s1 = __hip_atomic_load(&sq[(3 * n + 1) * TS + t], __ATOMIC_RELAXED, __HIP_MEMORY_SCOPE_AGENT);
        float s2 = __hip_atomic_load(&sq[(3 * n + 2) * TS + t], __ATOMIC_RELAXED, __HIP_MEMORY_SCOPE_AGENT);
        local += sqrtf(s0 + s1 + s2);
    }
    for (int off = 32; off > 0; off >>= 1)
        local += __shfl_down(local, off, 64);
    __shared__ float red[4];
    int lane = threadIdx.x & 63, wid = threadIdx.x >> 6;
    if (lane == 0) red[wid] = local;
    __syncthreads();
    if (threadIdx.x == 0) out[0] = red[0] + red[1] + red[2] + red[3];
}

extern "C" void kernel_launch(void* const* d_in, const int* in_sizes, int n_in,
                              void* d_out, int out_size, void* d_ws, size_t ws_size,
                              hipStream_t stream) {
    const float* src = (const float*)d_in[0];
    const float* tgt = (const float*)d_in[1];
    float* sq = (float*)d_ws;          // 8640 floats + 1 ticket
    float* out = (float*)d_out;

    pj_zero<<<(CT + 256) / 256, 256, 0, stream>>>(sq);
    pj_accum<<<NBLK, 256, 0, stream>>>(src, tgt, sq, out);
}

// Round 9
// 200.274 us; speedup vs baseline: 3.0141x; 3.0141x over previous
//
#include <hip/hip_runtime.h>
#include <math.h>

// Problem constants
#define NJ   24
#define JD   3
#define TS   120
#define B_TOT 16384
#define CT   (NJ * JD * TS)     // 8640 floats per batch row
#define CT4  (CT / 4)           // 2160 float4 per row
#define FL4_TOT ((long)B_TOT * CT4)  // 35,389,440 float4 total
#define NBLK 2160               // blocks; 2160*256 threads = 16 rows' worth of float4
#define THREADS (NBLK * 256)    // 552,960; THREADS % CT4 == 0 -> fixed per-thread position
#define ITERS ((int)(FL4_TOT / THREADS))  // 64, exact

typedef float vfloat4 __attribute__((ext_vector_type(4)));

__global__ void pj_zero(float* __restrict__ sq) {
    int i = blockIdx.x * blockDim.x + threadIdx.x;
    if (i < CT) sq[i] = 0.0f;
}

// Whole grid walks src/tgt as one contiguous sliding window (stride = THREADS
// float4 = 8.8 MB). THREADS is a multiple of CT4, so each thread's position
// within a row (p = tid mod CT4) is FIXED -> accumulate in registers, 4 atomics
// at the end. Per-instruction: lane i reads 16B at stride 16B -> perfect
// coalescing. nt loads bypass L2/L3 fill (zero-reuse stream): +7% proven R5.
// NO fence / NO fused finalize: a per-wave agent fence (buffer_wbl2) cost 3x (R8).
__global__ void pj_accum(const float* __restrict__ src,
                         const float* __restrict__ tgt,
                         float* __restrict__ sq) {
    int tid = blockIdx.x * 256 + threadIdx.x;
    int p = tid % CT4;              // fixed row-position of this thread
    const vfloat4* s = (const vfloat4*)src;
    const vfloat4* t = (const vfloat4*)tgt;
    long k = tid;
    float ax = 0.f, ay = 0.f, az = 0.f, aw = 0.f;
    #pragma unroll 8
    for (int j = 0; j < ITERS; ++j) {
        vfloat4 a = __builtin_nontemporal_load(&s[k]);
        vfloat4 c = __builtin_nontemporal_load(&t[k]);
        vfloat4 d = a - c;
        ax += d.x * d.x; ay += d.y * d.y; az += d.z * d.z; aw += d.w * d.w;
        k += THREADS;
    }
    atomicAdd(&sq[p * 4 + 0], ax);
    atomicAdd(&sq[p * 4 + 1], ay);
    atomicAdd(&sq[p * 4 + 2], az);
    atomicAdd(&sq[p * 4 + 3], aw);
}

__global__ void pj_finalize(const float* __restrict__ sq, float* __restrict__ out) {
    float local = 0.0f;
    // 2880 (n,t) cells; each sums 3 joint-dim rows then sqrt
    for (int i = threadIdx.x; i < NJ * TS; i += blockDim.x) {
        int n = i / TS, t = i - (i / TS) * TS;
        float s = sq[(3 * n + 0) * TS + t]
                + sq[(3 * n + 1) * TS + t]
                + sq[(3 * n + 2) * TS + t];
        local += sqrtf(s);
    }
    // wave reduce (64 lanes)
    for (int off = 32; off > 0; off >>= 1)
        local += __shfl_down(local, off, 64);
    __shared__ float red[4];
    int lane = threadIdx.x & 63, wid = threadIdx.x >> 6;
    if (lane == 0) red[wid] = local;
    __syncthreads();
    if (threadIdx.x == 0) {
        float tot = 0.f;
        int nw = blockDim.x >> 6;
        for (int w = 0; w < nw; ++w) tot += red[w];
        out[0] = tot;
    }
}

extern "C" void kernel_launch(void* const* d_in, const int* in_sizes, int n_in,
                              void* d_out, int out_size, void* d_ws, size_t ws_size,
                              hipStream_t stream) {
    const float* src = (const float*)d_in[0];
    const float* tgt = (const float*)d_in[1];
    float* sq = (float*)d_ws;          // 8640 floats = 34.6 KB scratch
    float* out = (float*)d_out;

    pj_zero<<<(CT + 255) / 256, 256, 0, stream>>>(sq);

    pj_accum<<<NBLK, 256, 0, stream>>>(src, tgt, sq);

    pj_finalize<<<1, 256, 0, stream>>>(sq, out);
}